// Round 1
// baseline (352.541 us; speedup 1.0000x reference)
//
#include <hip/hip_runtime.h>

#define TB 4
#define TF 4096
#define DIN 1024
#define DK 128
#define M_TOT (TB * TF)  // 16384

typedef __attribute__((ext_vector_type(8))) short sh8;
typedef __attribute__((ext_vector_type(4))) float f32x4;

__device__ __forceinline__ unsigned short f2bf(float f) {
  unsigned int u = __builtin_bit_cast(unsigned int, f);
  u += 0x7FFFu + ((u >> 16) & 1u);
  return (unsigned short)(u >> 16);
}

// Wt[p][n][k] = bf16(W_p[k][n]);  p in {q,k,v}
__global__ __launch_bounds__(256) void prep_wt_kernel(
    const float* __restrict__ Wq, const float* __restrict__ Wk,
    const float* __restrict__ Wv, unsigned short* __restrict__ Wt) {
  int idx = blockIdx.x * 256 + threadIdx.x;  // [0, 3*128*1024)
  int p = idx >> 17;
  int r = idx & 0x1FFFF;
  int n = r >> 10;
  int k = r & 1023;
  const float* W = (p == 0) ? Wq : (p == 1) ? Wk : Wv;
  Wt[idx] = f2bf(W[k * DK + n]);
}

// Fused QKV projection. Block = 64 rows of x, 4 waves each own 32 output cols
// for all 3 projections. Q is pre-scaled by 1/sqrt(128). V stored transposed.
__global__ __launch_bounds__(256) void proj_kernel(
    const float* __restrict__ x,            // [M_TOT][DIN]
    const unsigned short* __restrict__ Wt,  // [3][DK][DIN] bf16
    const float* __restrict__ bq, const float* __restrict__ bk,
    const float* __restrict__ bv,
    unsigned short* __restrict__ Qb,  // [M_TOT][DK] bf16 (pre-scaled)
    unsigned short* __restrict__ Kb,  // [M_TOT][DK] bf16
    unsigned short* __restrict__ VT)  // [TB][DK][TF] bf16
{
  const int tid = threadIdx.x;
  const int wave = tid >> 6;
  const int lane = tid & 63;
  const int lr = lane & 15;
  const int lg = lane >> 4;
  const int m0 = blockIdx.x * 64;

  f32x4 acc[3][4][2];
  const f32x4 z4 = {0.f, 0.f, 0.f, 0.f};
#pragma unroll
  for (int p = 0; p < 3; ++p)
#pragma unroll
    for (int m = 0; m < 4; ++m)
#pragma unroll
      for (int n = 0; n < 2; ++n) acc[p][m][n] = z4;

  for (int k0 = 0; k0 < DIN; k0 += 32) {
    sh8 a[4];
#pragma unroll
    for (int m = 0; m < 4; ++m) {
      const float* xp = x + (size_t)(m0 + m * 16 + lr) * DIN + k0 + lg * 8;
      float4 f0 = *(const float4*)xp;
      float4 f1 = *(const float4*)(xp + 4);
      union { sh8 v; unsigned short u[8]; } U;
      U.u[0] = f2bf(f0.x); U.u[1] = f2bf(f0.y);
      U.u[2] = f2bf(f0.z); U.u[3] = f2bf(f0.w);
      U.u[4] = f2bf(f1.x); U.u[5] = f2bf(f1.y);
      U.u[6] = f2bf(f1.z); U.u[7] = f2bf(f1.w);
      a[m] = U.v;
    }
#pragma unroll
    for (int p = 0; p < 3; ++p) {
#pragma unroll
      for (int n = 0; n < 2; ++n) {
        const int col = wave * 32 + n * 16 + lr;
        sh8 b = *(const sh8*)(Wt + ((size_t)p * DK + col) * DIN + k0 + lg * 8);
#pragma unroll
        for (int m = 0; m < 4; ++m)
          acc[p][m][n] = __builtin_amdgcn_mfma_f32_16x16x32_bf16(
              a[m], b, acc[p][m][n], 0, 0, 0);
      }
    }
  }

  const float scale = 0.08838834764831845f;  // 1/sqrt(128)
  const int b_idx = m0 >> 12;
#pragma unroll
  for (int n = 0; n < 2; ++n) {
    const int col = wave * 32 + n * 16 + lr;
    const float add_q = bq[col];
    const float add_k = bk[col];
    const float add_v = bv[col];
#pragma unroll
    for (int m = 0; m < 4; ++m) {
      const int rowbase = m0 + m * 16 + lg * 4;
#pragma unroll
      for (int r = 0; r < 4; ++r) {
        Qb[(size_t)(rowbase + r) * DK + col] =
            f2bf((acc[0][m][n][r] + add_q) * scale);
        Kb[(size_t)(rowbase + r) * DK + col] = f2bf(acc[1][m][n][r] + add_k);
      }
      const int fbase = (m0 & (TF - 1)) + m * 16 + lg * 4;
      ushort4 pv;
      pv.x = f2bf(acc[2][m][n][0] + add_v);
      pv.y = f2bf(acc[2][m][n][1] + add_v);
      pv.z = f2bf(acc[2][m][n][2] + add_v);
      pv.w = f2bf(acc[2][m][n][3] + add_v);
      *(ushort4*)(VT + ((size_t)b_idx * DK + col) * TF + fbase) = pv;
    }
  }
}

// Flash attention: 4 waves/block, each wave owns 16 q-rows, KVBLK = 64.
__global__ __launch_bounds__(256) void attn_kernel(
    const unsigned short* __restrict__ Qb, const unsigned short* __restrict__ Kb,
    const unsigned short* __restrict__ VT, float* __restrict__ out) {
  const int tid = threadIdx.x;
  const int wave = tid >> 6;
  const int lane = tid & 63;
  const int lr = lane & 15;
  const int lg = lane >> 4;

  // XCD swizzle: 256 blocks round-robin over 8 XCDs; give each XCD one batch
  // (2 XCDs per batch) so K/V (2 MB/batch) stays L2-resident per XCD.
  const int bid = blockIdx.x;
  const int xcd = bid & 7;
  const int batch = xcd >> 1;
  const int slot = ((bid >> 3) << 1) | (xcd & 1);  // 0..63
  const int q0 = batch * TF + slot * 64 + wave * 16;

  __shared__ unsigned short Klds[64 * 136];   // 64 kv rows x 128 d (pad->136)
  __shared__ unsigned short Vlds[128 * 72];   // 128 dv rows x 64 kv (pad->72)
  __shared__ unsigned short Plds[4][16 * 72]; // per-wave P transpose buffer

  const unsigned short* Qp = Qb + (size_t)q0 * DK;
  const unsigned short* Kp = Kb + (size_t)batch * TF * DK;
  const unsigned short* Vp = VT + (size_t)batch * DK * TF;

  sh8 aq[4];
#pragma unroll
  for (int dd = 0; dd < 4; ++dd)
    aq[dd] = *(const sh8*)(Qp + lr * DK + dd * 32 + lg * 8);

  const f32x4 z4 = {0.f, 0.f, 0.f, 0.f};
  f32x4 o[8];
#pragma unroll
  for (int nb = 0; nb < 8; ++nb) o[nb] = z4;
  float mrow[4], lrow[4];
#pragma unroll
  for (int r = 0; r < 4; ++r) { mrow[r] = -1e30f; lrow[r] = 0.f; }

  for (int kk0 = 0; kk0 < TF; kk0 += 64) {
    __syncthreads();
#pragma unroll
    for (int i = 0; i < 4; ++i) {  // stage K tile 64x128
      int c = tid + i * 256;
      int row = c >> 4, c8 = c & 15;
      *(uint4*)&Klds[row * 136 + c8 * 8] =
          *(const uint4*)(Kp + (size_t)(kk0 + row) * DK + c8 * 8);
    }
#pragma unroll
    for (int i = 0; i < 4; ++i) {  // stage V^T tile 128x64
      int c = tid + i * 256;
      int row = c >> 3, c8 = c & 7;
      *(uint4*)&Vlds[row * 72 + c8 * 8] =
          *(const uint4*)(Vp + (size_t)row * TF + kk0 + c8 * 8);
    }
    __syncthreads();

    // S = Q K^T  (16 q x 64 kv)
    f32x4 s[4];
#pragma unroll
    for (int c = 0; c < 4; ++c) s[c] = z4;
#pragma unroll
    for (int dd = 0; dd < 4; ++dd) {
#pragma unroll
      for (int c = 0; c < 4; ++c) {
        sh8 kb = *(const sh8*)&Klds[(c * 16 + lr) * 136 + dd * 32 + lg * 8];
        s[c] = __builtin_amdgcn_mfma_f32_16x16x32_bf16(aq[dd], kb, s[c], 0, 0, 0);
      }
    }

    // online softmax (per register r = q row lg*4+r)
    float p[4][4];
    float al[4];
#pragma unroll
    for (int r = 0; r < 4; ++r) {
      float mx = fmaxf(fmaxf(s[0][r], s[1][r]), fmaxf(s[2][r], s[3][r]));
      mx = fmaxf(mx, __shfl_xor(mx, 1));
      mx = fmaxf(mx, __shfl_xor(mx, 2));
      mx = fmaxf(mx, __shfl_xor(mx, 4));
      mx = fmaxf(mx, __shfl_xor(mx, 8));
      const float mnew = fmaxf(mrow[r], mx);
      al[r] = __expf(mrow[r] - mnew);
      float rs = 0.f;
#pragma unroll
      for (int c = 0; c < 4; ++c) {
        p[c][r] = __expf(s[c][r] - mnew);
        rs += p[c][r];
      }
      rs += __shfl_xor(rs, 1);
      rs += __shfl_xor(rs, 2);
      rs += __shfl_xor(rs, 4);
      rs += __shfl_xor(rs, 8);
      lrow[r] = lrow[r] * al[r] + rs;
      mrow[r] = mnew;
    }
#pragma unroll
    for (int nb = 0; nb < 8; ++nb)
#pragma unroll
      for (int r = 0; r < 4; ++r) o[nb][r] *= al[r];

    // P -> LDS (transpose to A-fragment layout), bf16
#pragma unroll
    for (int c = 0; c < 4; ++c)
#pragma unroll
      for (int r = 0; r < 4; ++r)
        Plds[wave][(lg * 4 + r) * 72 + c * 16 + lr] = f2bf(p[c][r]);

    // O += P V
#pragma unroll
    for (int ks = 0; ks < 2; ++ks) {
      sh8 pa = *(const sh8*)&Plds[wave][lr * 72 + ks * 32 + lg * 8];
#pragma unroll
      for (int nb = 0; nb < 8; ++nb) {
        sh8 vb = *(const sh8*)&Vlds[(nb * 16 + lr) * 72 + ks * 32 + lg * 8];
        o[nb] = __builtin_amdgcn_mfma_f32_16x16x32_bf16(pa, vb, o[nb], 0, 0, 0);
      }
    }
  }

  float inv[4];
#pragma unroll
  for (int r = 0; r < 4; ++r) inv[r] = 1.0f / lrow[r];
#pragma unroll
  for (int nb = 0; nb < 8; ++nb)
#pragma unroll
    for (int r = 0; r < 4; ++r)
      out[(size_t)(q0 + lg * 4 + r) * DK + nb * 16 + lr] = o[nb][r] * inv[r];
}

extern "C" void kernel_launch(void* const* d_in, const int* in_sizes, int n_in,
                              void* d_out, int out_size, void* d_ws,
                              size_t ws_size, hipStream_t stream) {
  const float* x = (const float*)d_in[0];
  const float* Wq = (const float*)d_in[1];
  const float* bq = (const float*)d_in[2];
  const float* Wk = (const float*)d_in[3];
  const float* bk = (const float*)d_in[4];
  const float* Wv = (const float*)d_in[5];
  const float* bv = (const float*)d_in[6];
  float* out = (float*)d_out;

  unsigned short* Wt = (unsigned short*)d_ws;              // 3*128*1024*2 = 768 KB
  unsigned short* Qb = Wt + 3 * DK * DIN;                  // 4 MB
  unsigned short* Kb = Qb + (size_t)M_TOT * DK;            // 4 MB
  unsigned short* VT = Kb + (size_t)M_TOT * DK;            // 4 MB

  prep_wt_kernel<<<(3 * DK * DIN) / 256, 256, 0, stream>>>(Wq, Wk, Wv, Wt);
  proj_kernel<<<M_TOT / 64, 256, 0, stream>>>(x, Wt, bq, bk, bv, Qb, Kb, VT);
  attn_kernel<<<M_TOT / 64, 256, 0, stream>>>(Qb, Kb, VT, out);
}

// Round 3
// 230.544 us; speedup vs baseline: 1.5292x; 1.5292x over previous
//
#include <hip/hip_runtime.h>

#define TB 4
#define TF 4096
#define DIN 1024
#define DK 128
#define M_TOT (TB * TF)  // 16384

typedef __attribute__((ext_vector_type(8))) short sh8;
typedef __attribute__((ext_vector_type(4))) float f32x4;

__device__ __forceinline__ unsigned short f2bf(float f) {
  unsigned int u = __builtin_bit_cast(unsigned int, f);
  u += 0x7FFFu + ((u >> 16) & 1u);
  return (unsigned short)(u >> 16);
}

// Wt[p][n][k] = bf16(W_p[k][n]);  p in {q,k,v}
__global__ __launch_bounds__(256) void prep_wt_kernel(
    const float* __restrict__ Wq, const float* __restrict__ Wk,
    const float* __restrict__ Wv, unsigned short* __restrict__ Wt) {
  int idx = blockIdx.x * 256 + threadIdx.x;  // [0, 3*128*1024)
  int p = idx >> 17;
  int r = idx & 0x1FFFF;
  int n = r >> 10;
  int k = r & 1023;
  const float* W = (p == 0) ? Wq : (p == 1) ? Wk : Wv;
  Wt[idx] = f2bf(W[k * DK + n]);
}

// Fused QKV projection. Block = 64 rows of x, 4 waves each own 32 output cols
// for all 3 projections. Q is pre-scaled by 1/sqrt(128). V stored transposed.
__global__ __launch_bounds__(256) void proj_kernel(
    const float* __restrict__ x,            // [M_TOT][DIN]
    const unsigned short* __restrict__ Wt,  // [3][DK][DIN] bf16
    const float* __restrict__ bq, const float* __restrict__ bk,
    const float* __restrict__ bv,
    unsigned short* __restrict__ Qb,  // [M_TOT][DK] bf16 (pre-scaled)
    unsigned short* __restrict__ Kb,  // [M_TOT][DK] bf16
    unsigned short* __restrict__ VT)  // [TB][DK][TF] bf16
{
  const int tid = threadIdx.x;
  const int wave = tid >> 6;
  const int lane = tid & 63;
  const int lr = lane & 15;
  const int lg = lane >> 4;
  const int m0 = blockIdx.x * 64;

  f32x4 acc[3][4][2];
  const f32x4 z4 = {0.f, 0.f, 0.f, 0.f};
#pragma unroll
  for (int p = 0; p < 3; ++p)
#pragma unroll
    for (int m = 0; m < 4; ++m)
#pragma unroll
      for (int n = 0; n < 2; ++n) acc[p][m][n] = z4;

  for (int k0 = 0; k0 < DIN; k0 += 32) {
    sh8 a[4];
#pragma unroll
    for (int m = 0; m < 4; ++m) {
      const float* xp = x + (size_t)(m0 + m * 16 + lr) * DIN + k0 + lg * 8;
      float4 f0 = *(const float4*)xp;
      float4 f1 = *(const float4*)(xp + 4);
      union { sh8 v; unsigned short u[8]; } U;
      U.u[0] = f2bf(f0.x); U.u[1] = f2bf(f0.y);
      U.u[2] = f2bf(f0.z); U.u[3] = f2bf(f0.w);
      U.u[4] = f2bf(f1.x); U.u[5] = f2bf(f1.y);
      U.u[6] = f2bf(f1.z); U.u[7] = f2bf(f1.w);
      a[m] = U.v;
    }
#pragma unroll
    for (int p = 0; p < 3; ++p) {
#pragma unroll
      for (int n = 0; n < 2; ++n) {
        const int col = wave * 32 + n * 16 + lr;
        sh8 b = *(const sh8*)(Wt + ((size_t)p * DK + col) * DIN + k0 + lg * 8);
#pragma unroll
        for (int m = 0; m < 4; ++m)
          acc[p][m][n] = __builtin_amdgcn_mfma_f32_16x16x32_bf16(
              a[m], b, acc[p][m][n], 0, 0, 0);
      }
    }
  }

  const float scale = 0.08838834764831845f;  // 1/sqrt(128)
  const int b_idx = m0 >> 12;
#pragma unroll
  for (int n = 0; n < 2; ++n) {
    const int col = wave * 32 + n * 16 + lr;
    const float add_q = bq[col];
    const float add_k = bk[col];
    const float add_v = bv[col];
#pragma unroll
    for (int m = 0; m < 4; ++m) {
      const int rowbase = m0 + m * 16 + lg * 4;
#pragma unroll
      for (int r = 0; r < 4; ++r) {
        Qb[(size_t)(rowbase + r) * DK + col] =
            f2bf((acc[0][m][n][r] + add_q) * scale);
        Kb[(size_t)(rowbase + r) * DK + col] = f2bf(acc[1][m][n][r] + add_k);
      }
      const int fbase = (m0 & (TF - 1)) + m * 16 + lg * 4;
      ushort4 pv;
      pv.x = f2bf(acc[2][m][n][0] + add_v);
      pv.y = f2bf(acc[2][m][n][1] + add_v);
      pv.z = f2bf(acc[2][m][n][2] + add_v);
      pv.w = f2bf(acc[2][m][n][3] + add_v);
      *(ushort4*)(VT + ((size_t)b_idx * DK + col) * TF + fbase) = pv;
    }
  }
}

// Flash attention with split-KV. 4 waves/block, each wave owns 16 q-rows,
// KVBLK = 64, each block covers a KV chunk of TF/SPLIT.
// LDS = 17408 (K) + 18432 (V) + 9216 (P) = 45056 B -> 3 blocks/CU.
template <int SPLIT>
__global__ __launch_bounds__(256) void attn_part_kernel(
    const unsigned short* __restrict__ Qb, const unsigned short* __restrict__ Kb,
    const unsigned short* __restrict__ VT, float* __restrict__ Opart,
    float* __restrict__ Mpart, float* __restrict__ Lpart,
    float* __restrict__ out) {
  constexpr int CHUNK = TF / SPLIT;
  const int tid = threadIdx.x;
  const int wave = tid >> 6;
  const int lane = tid & 63;
  const int lr = lane & 15;
  const int lg = lane >> 4;

  // XCD swizzle: blocks round-robin over 8 XCDs; 2 XCDs per batch so K/V
  // (2 MB bf16/batch) stays L2-resident per XCD.
  const int bid = blockIdx.x;
  const int xcd = bid & 7;
  const int batch = xcd >> 1;
  const int idb = ((bid >> 3) << 1) | (xcd & 1);  // 0 .. 64*SPLIT-1
  const int slot = idb / SPLIT;
  const int chunk = idb % SPLIT;
  const int q0 = batch * TF + slot * 64 + wave * 16;
  const int kbase = chunk * CHUNK;

  __shared__ unsigned short Klds[64 * 136];   // 64 kv rows x 128 d (pad->136)
  __shared__ unsigned short Vlds[128 * 72];   // 128 dv rows x 64 kv (pad->72)
  __shared__ unsigned short Plds[4][16 * 72]; // per-wave P transpose buffer

  const unsigned short* Qp = Qb + (size_t)q0 * DK;
  const unsigned short* Kp = Kb + (size_t)batch * TF * DK;
  const unsigned short* Vp = VT + (size_t)batch * DK * TF;

  sh8 aq[4];
#pragma unroll
  for (int dd = 0; dd < 4; ++dd)
    aq[dd] = *(const sh8*)(Qp + lr * DK + dd * 32 + lg * 8);

  const f32x4 z4 = {0.f, 0.f, 0.f, 0.f};
  f32x4 o[8];
#pragma unroll
  for (int nb = 0; nb < 8; ++nb) o[nb] = z4;
  float mrow[4], lrow[4];
#pragma unroll
  for (int r = 0; r < 4; ++r) { mrow[r] = -1e30f; lrow[r] = 0.f; }

  for (int kk0 = kbase; kk0 < kbase + CHUNK; kk0 += 64) {
    __syncthreads();
#pragma unroll
    for (int i = 0; i < 4; ++i) {  // stage K tile 64x128
      int c = tid + i * 256;
      int row = c >> 4, c8 = c & 15;
      *(uint4*)&Klds[row * 136 + c8 * 8] =
          *(const uint4*)(Kp + (size_t)(kk0 + row) * DK + c8 * 8);
    }
#pragma unroll
    for (int i = 0; i < 4; ++i) {  // stage V^T tile 128x64
      int c = tid + i * 256;
      int row = c >> 3, c8 = c & 7;
      *(uint4*)&Vlds[row * 72 + c8 * 8] =
          *(const uint4*)(Vp + (size_t)row * TF + kk0 + c8 * 8);
    }
    __syncthreads();

    // S = Q K^T  (16 q x 64 kv)
    f32x4 s[4];
#pragma unroll
    for (int c = 0; c < 4; ++c) s[c] = z4;
#pragma unroll
    for (int dd = 0; dd < 4; ++dd) {
#pragma unroll
      for (int c = 0; c < 4; ++c) {
        sh8 kb = *(const sh8*)&Klds[(c * 16 + lr) * 136 + dd * 32 + lg * 8];
        s[c] = __builtin_amdgcn_mfma_f32_16x16x32_bf16(aq[dd], kb, s[c], 0, 0, 0);
      }
    }

    // online softmax (per register r = q row lg*4+r)
    float p[4][4];
    float al[4];
#pragma unroll
    for (int r = 0; r < 4; ++r) {
      float mx = fmaxf(fmaxf(s[0][r], s[1][r]), fmaxf(s[2][r], s[3][r]));
      mx = fmaxf(mx, __shfl_xor(mx, 1));
      mx = fmaxf(mx, __shfl_xor(mx, 2));
      mx = fmaxf(mx, __shfl_xor(mx, 4));
      mx = fmaxf(mx, __shfl_xor(mx, 8));
      const float mnew = fmaxf(mrow[r], mx);
      al[r] = __expf(mrow[r] - mnew);
      float rs = 0.f;
#pragma unroll
      for (int c = 0; c < 4; ++c) {
        p[c][r] = __expf(s[c][r] - mnew);
        rs += p[c][r];
      }
      rs += __shfl_xor(rs, 1);
      rs += __shfl_xor(rs, 2);
      rs += __shfl_xor(rs, 4);
      rs += __shfl_xor(rs, 8);
      lrow[r] = lrow[r] * al[r] + rs;
      mrow[r] = mnew;
    }
#pragma unroll
    for (int nb = 0; nb < 8; ++nb)
#pragma unroll
      for (int r = 0; r < 4; ++r) o[nb][r] *= al[r];

    // P -> LDS (transpose to A-fragment layout), bf16
#pragma unroll
    for (int c = 0; c < 4; ++c)
#pragma unroll
      for (int r = 0; r < 4; ++r)
        Plds[wave][(lg * 4 + r) * 72 + c * 16 + lr] = f2bf(p[c][r]);

    // O += P V
#pragma unroll
    for (int ks = 0; ks < 2; ++ks) {
      sh8 pa = *(const sh8*)&Plds[wave][lr * 72 + ks * 32 + lg * 8];
#pragma unroll
      for (int nb = 0; nb < 8; ++nb) {
        sh8 vb = *(const sh8*)&Vlds[(nb * 16 + lr) * 72 + ks * 32 + lg * 8];
        o[nb] = __builtin_amdgcn_mfma_f32_16x16x32_bf16(pa, vb, o[nb], 0, 0, 0);
      }
    }
  }

  if constexpr (SPLIT == 1) {
    float inv[4];
#pragma unroll
    for (int r = 0; r < 4; ++r) inv[r] = 1.0f / lrow[r];
#pragma unroll
    for (int nb = 0; nb < 8; ++nb)
#pragma unroll
      for (int r = 0; r < 4; ++r)
        out[(size_t)(q0 + lg * 4 + r) * DK + nb * 16 + lr] = o[nb][r] * inv[r];
  } else {
#pragma unroll
    for (int r = 0; r < 4; ++r) {
      const int row = q0 + lg * 4 + r;
      if (lr == 0) {
        Mpart[(size_t)chunk * M_TOT + row] = mrow[r];
        Lpart[(size_t)chunk * M_TOT + row] = lrow[r];
      }
#pragma unroll
      for (int nb = 0; nb < 8; ++nb)
        Opart[((size_t)chunk * M_TOT + row) * DK + nb * 16 + lr] = o[nb][r];
    }
  }
}

__global__ __launch_bounds__(256) void combine_kernel(
    const float* __restrict__ Opart, const float* __restrict__ Mpart,
    const float* __restrict__ Lpart, float* __restrict__ out, int split) {
  const int idx = blockIdx.x * 256 + threadIdx.x;  // M_TOT * 32
  const int row = idx >> 5;
  const int cq = (idx & 31) << 2;
  float m = -1e30f;
  for (int s = 0; s < split; ++s) m = fmaxf(m, Mpart[(size_t)s * M_TOT + row]);
  float den = 0.f;
  float4 acc = {0.f, 0.f, 0.f, 0.f};
  for (int s = 0; s < split; ++s) {
    const float w = __expf(Mpart[(size_t)s * M_TOT + row] - m);
    den += w * Lpart[(size_t)s * M_TOT + row];
    const float4 v = *(const float4*)(Opart + ((size_t)s * M_TOT + row) * DK + cq);
    acc.x += w * v.x; acc.y += w * v.y; acc.z += w * v.z; acc.w += w * v.w;
  }
  const float inv = 1.0f / den;
  float4 res = {acc.x * inv, acc.y * inv, acc.z * inv, acc.w * inv};
  *(float4*)(out + (size_t)row * DK + cq) = res;
}

extern "C" void kernel_launch(void* const* d_in, const int* in_sizes, int n_in,
                              void* d_out, int out_size, void* d_ws,
                              size_t ws_size, hipStream_t stream) {
  const float* x = (const float*)d_in[0];
  const float* Wq = (const float*)d_in[1];
  const float* bq = (const float*)d_in[2];
  const float* Wk = (const float*)d_in[3];
  const float* bk = (const float*)d_in[4];
  const float* Wv = (const float*)d_in[5];
  const float* bv = (const float*)d_in[6];
  float* out = (float*)d_out;

  unsigned short* Wt = (unsigned short*)d_ws;              // 768 KB
  unsigned short* Qb = Wt + 3 * DK * DIN;                  // 4 MB
  unsigned short* Kb = Qb + (size_t)M_TOT * DK;            // 4 MB
  unsigned short* VT = Kb + (size_t)M_TOT * DK;            // 4 MB
  float* Opart = (float*)(VT + (size_t)M_TOT * DK);        // split*8 MB
  const size_t base_bytes = 2ull * (3 * DK * DIN + 3ull * M_TOT * DK);
  const size_t per_split = (size_t)M_TOT * DK * 4 + 2ull * M_TOT * 4;

  prep_wt_kernel<<<(3 * DK * DIN) / 256, 256, 0, stream>>>(Wq, Wk, Wv, Wt);
  proj_kernel<<<M_TOT / 64, 256, 0, stream>>>(x, Wt, bq, bk, bv, Qb, Kb, VT);

  int split;
  if (ws_size >= base_bytes + 4 * per_split) split = 4;
  else if (ws_size >= base_bytes + 2 * per_split) split = 2;
  else split = 1;

  float* Mpart = Opart + (size_t)split * M_TOT * DK;
  float* Lpart = Mpart + (size_t)split * M_TOT;

  if (split == 4) {
    attn_part_kernel<4><<<256 * 4, 256, 0, stream>>>(Qb, Kb, VT, Opart, Mpart,
                                                     Lpart, out);
    combine_kernel<<<M_TOT * 32 / 256, 256, 0, stream>>>(Opart, Mpart, Lpart,
                                                         out, 4);
  } else if (split == 2) {
    attn_part_kernel<2><<<256 * 2, 256, 0, stream>>>(Qb, Kb, VT, Opart, Mpart,
                                                     Lpart, out);
    combine_kernel<<<M_TOT * 32 / 256, 256, 0, stream>>>(Opart, Mpart, Lpart,
                                                         out, 2);
  } else {
    attn_part_kernel<1><<<256, 256, 0, stream>>>(Qb, Kb, VT, nullptr, nullptr,
                                                 nullptr, out);
  }
}